// Round 1
// baseline (2004.108 us; speedup 1.0000x reference)
//
#include <hip/hip_runtime.h>
#include <hip/hip_bf16.h>
#include <cmath>

#define NS 512   // n_stocks (sequence length of the attention)
#define NT 512   // tau (batch)
#define DIM 64
#define HD 32

// 4-way-split dot product over 64 elements; xr must be a register array
// (static indices after inlining+unroll). Breaks the 4-cyc FMA dep chain.
__device__ __forceinline__ float dot64(const float* __restrict__ w, const float* xr) {
  float a0 = 0.f, a1 = 0.f, a2 = 0.f, a3 = 0.f;
  #pragma unroll
  for (int j = 0; j < 16; ++j) {
    a0 = fmaf(w[4 * j + 0], xr[4 * j + 0], a0);
    a1 = fmaf(w[4 * j + 1], xr[4 * j + 1], a1);
    a2 = fmaf(w[4 * j + 2], xr[4 * j + 2], a2);
    a3 = fmaf(w[4 * j + 3], xr[4 * j + 3], a3);
  }
  return (a0 + a1) + (a2 + a3);
}

// ---------------- K0: transpose W2 (64x256) -> W2T (256x64) ----------------
__global__ void k_transpose_w2(const float* __restrict__ W2, float* __restrict__ W2T) {
  int idx = blockIdx.x * 256 + threadIdx.x;  // 16384 elements
  int d = idx >> 8;    // 0..63
  int j = idx & 255;   // 0..255
  W2T[j * 64 + d] = W2[d * 256 + j];
}

// ---------------- K1: fused QKV + attention, one block per (t, h) ----------
// block = 512 threads (1 thread per query). K rows in LDS (64 KB, broadcast
// reads -> conflict free). V rows in ws global (wave-uniform addresses ->
// scalar loads). ctx overwrites this block's V region after a barrier.
__global__ __launch_bounds__(512) void k_attn(
    const float* __restrict__ x, const float* __restrict__ Wqkv,
    const float* __restrict__ bqkv, float* __restrict__ vbuf) {
  extern __shared__ float Kl[];  // [512][32] fp32 = 64 KB
  const int t = blockIdx.x, h = blockIdx.y, s = threadIdx.x;

  // --- load this stock's x row (64 floats, contiguous) ---
  float xr[64];
  {
    const float4* xp = reinterpret_cast<const float4*>(x + ((size_t)s * NT + t) * DIM);
    #pragma unroll
    for (int i = 0; i < 16; ++i) {
      float4 v = xp[i];
      xr[4 * i + 0] = v.x; xr[4 * i + 1] = v.y;
      xr[4 * i + 2] = v.z; xr[4 * i + 3] = v.w;
    }
  }

  // --- q: fully unrolled so q[] stays in registers (static indices) ---
  float q[32];
  {
    const float* wq = Wqkv + (size_t)(h * HD) * DIM;
    const float* bq = bqkv + h * HD;
    #pragma unroll
    for (int d = 0; d < 32; ++d) {
      q[d] = (dot64(wq + d * DIM, xr) + bq[d]) * 0.17677669529663687f; // 1/sqrt(32)
    }
  }

  // --- k, v: 4 outputs at a time (float4 temp keeps indices static) ---
  float* vrow_out = vbuf + ((size_t)(t * 2 + h) * NS + s) * HD;
  {
    const float* wk = Wqkv + (size_t)(64 + h * HD) * DIM;
    const float* wv = Wqkv + (size_t)(128 + h * HD) * DIM;
    const float* bk = bqkv + 64 + h * HD;
    const float* bv = bqkv + 128 + h * HD;
    #pragma clang loop unroll(disable)
    for (int c = 0; c < 8; ++c) {
      float kc[4], vc[4];
      #pragma unroll
      for (int u = 0; u < 4; ++u) {
        int d = c * 4 + u;
        kc[u] = dot64(wk + d * DIM, xr) + bk[d];
        vc[u] = dot64(wv + d * DIM, xr) + bv[d];
      }
      *reinterpret_cast<float4*>(&Kl[s * HD + c * 4]) = make_float4(kc[0], kc[1], kc[2], kc[3]);
      *reinterpret_cast<float4*>(vrow_out + c * 4)   = make_float4(vc[0], vc[1], vc[2], vc[3]);
    }
  }
  __syncthreads();

  // --- online-softmax attention over all 512 keys ---
  const float* vb = vbuf + (size_t)(t * 2 + h) * NS * HD;
  float m = -INFINITY, l = 0.f;
  float acc[32];
  #pragma unroll
  for (int d = 0; d < 32; ++d) acc[d] = 0.f;

  #pragma clang loop unroll_count(2)
  for (int k = 0; k < NS; ++k) {
    // K row: all lanes read the same address -> LDS broadcast, no conflicts
    float kr[32];
    {
      const float4* kp = reinterpret_cast<const float4*>(Kl + k * HD);
      #pragma unroll
      for (int i = 0; i < 8; ++i) {
        float4 v = kp[i];
        kr[4 * i + 0] = v.x; kr[4 * i + 1] = v.y;
        kr[4 * i + 2] = v.z; kr[4 * i + 3] = v.w;
      }
    }
    float s0 = 0.f, s1 = 0.f, s2 = 0.f, s3 = 0.f;
    #pragma unroll
    for (int j = 0; j < 8; ++j) {
      s0 = fmaf(q[4 * j + 0], kr[4 * j + 0], s0);
      s1 = fmaf(q[4 * j + 1], kr[4 * j + 1], s1);
      s2 = fmaf(q[4 * j + 2], kr[4 * j + 2], s2);
      s3 = fmaf(q[4 * j + 3], kr[4 * j + 3], s3);
    }
    float sc = (s0 + s1) + (s2 + s3);

    // V row: wave-uniform address -> scalar loads, no LDS/VGPR pressure
    const float* vr = vb + (size_t)k * HD;

    if (sc > m) {               // rarely taken after warm-up (~200/512 iters)
      float corr = __expf(m - sc);   // m = -inf on first iter -> corr = 0
      l *= corr;
      #pragma unroll
      for (int d = 0; d < 32; ++d) acc[d] *= corr;
      m = sc;
    }
    float p = __expf(sc - m);
    l += p;
    #pragma unroll
    for (int d = 0; d < 32; ++d) acc[d] = fmaf(p, vr[d], acc[d]);
  }

  // --- all waves done reading V -> safe to overwrite with ctx ---
  __syncthreads();
  float inv = 1.f / l;
  float4* co = reinterpret_cast<float4*>(vrow_out);
  #pragma unroll
  for (int c = 0; c < 8; ++c)
    co[c] = make_float4(acc[4 * c + 0] * inv, acc[4 * c + 1] * inv,
                        acc[4 * c + 2] * inv, acc[4 * c + 3] * inv);
}

// ---------------- K2: fused Wo-proj + LN1 + FFN + LN2 + transpose ----------
// One thread per (t, s) row. Activations live in registers with static
// indices; attn_out staged in a per-thread LDS column (runtime-d indexing).
__global__ __launch_bounds__(256) void k_tail(
    const float* __restrict__ cbuf,   // ctx, layout (t, h, s, 32)
    const float* __restrict__ x,
    const float* __restrict__ Wo, const float* __restrict__ bo,
    const float* __restrict__ g1, const float* __restrict__ be1,
    const float* __restrict__ W1, const float* __restrict__ bf1,
    const float* __restrict__ W2T, const float* __restrict__ bf2,
    const float* __restrict__ g2, const float* __restrict__ be2,
    float* __restrict__ out) {
  extern __shared__ float aout[];  // [64][256] = 64 KB, column per thread
  const int tid = threadIdx.x;
  const size_t r = (size_t)blockIdx.x * 256 + tid;
  const int t = (int)(r >> 9), s = (int)(r & 511);

  // --- gather ctx row (two heads) ---
  float c[64];
  {
    const float4* p0 = reinterpret_cast<const float4*>(cbuf + ((size_t)(t * 2 + 0) * NS + s) * HD);
    const float4* p1 = reinterpret_cast<const float4*>(cbuf + ((size_t)(t * 2 + 1) * NS + s) * HD);
    #pragma unroll
    for (int i = 0; i < 8; ++i) {
      float4 v = p0[i];
      c[4 * i + 0] = v.x; c[4 * i + 1] = v.y; c[4 * i + 2] = v.z; c[4 * i + 3] = v.w;
    }
    #pragma unroll
    for (int i = 0; i < 8; ++i) {
      float4 v = p1[i];
      c[32 + 4 * i + 0] = v.x; c[32 + 4 * i + 1] = v.y;
      c[32 + 4 * i + 2] = v.z; c[32 + 4 * i + 3] = v.w;
    }
  }

  // --- attn_out = Wo @ ctx + bo  -> own LDS column (no barrier needed) ---
  #pragma clang loop unroll(disable)
  for (int d = 0; d < 64; ++d) {
    aout[d * 256 + tid] = dot64(Wo + d * 64, c) + bo[d];
  }

  // --- residual + LN1 ---
  float y[64];
  {
    const float4* xp = reinterpret_cast<const float4*>(x + ((size_t)s * NT + t) * DIM);
    #pragma unroll
    for (int i = 0; i < 16; ++i) {
      float4 v = xp[i];
      y[4 * i + 0] = v.x + aout[(4 * i + 0) * 256 + tid];
      y[4 * i + 1] = v.y + aout[(4 * i + 1) * 256 + tid];
      y[4 * i + 2] = v.z + aout[(4 * i + 2) * 256 + tid];
      y[4 * i + 3] = v.w + aout[(4 * i + 3) * 256 + tid];
    }
  }
  {
    float m0 = 0.f, m1 = 0.f, m2 = 0.f, m3 = 0.f;
    #pragma unroll
    for (int j = 0; j < 16; ++j) {
      m0 += y[4 * j + 0]; m1 += y[4 * j + 1]; m2 += y[4 * j + 2]; m3 += y[4 * j + 3];
    }
    float mu = ((m0 + m1) + (m2 + m3)) * (1.f / 64.f);
    float v0 = 0.f, v1 = 0.f, v2 = 0.f, v3 = 0.f;
    #pragma unroll
    for (int j = 0; j < 16; ++j) {
      float t0 = y[4 * j + 0] - mu, t1 = y[4 * j + 1] - mu;
      float t2 = y[4 * j + 2] - mu, t3 = y[4 * j + 3] - mu;
      v0 = fmaf(t0, t0, v0); v1 = fmaf(t1, t1, v1);
      v2 = fmaf(t2, t2, v2); v3 = fmaf(t3, t3, v3);
    }
    float var = ((v0 + v1) + (v2 + v3)) * (1.f / 64.f);
    float rs = rsqrtf(var + 1e-5f);
    #pragma unroll
    for (int d = 0; d < 64; ++d) y[d] = (y[d] - mu) * rs * g1[d] + be1[d];
  }

  // --- FFN: h_j = relu(W1[j]·y + bf1[j]); z += W2T[j]·h_j (streamed) ---
  float z[64];
  #pragma unroll
  for (int d = 0; d < 64; ++d) z[d] = 0.f;
  #pragma clang loop unroll_count(2)
  for (int j = 0; j < 256; ++j) {
    float a = dot64(W1 + j * 64, y) + bf1[j];
    a = fmaxf(a, 0.f);
    const float* w2r = W2T + j * 64;
    #pragma unroll
    for (int d = 0; d < 64; ++d) z[d] = fmaf(w2r[d], a, z[d]);
  }

  // --- + bf2 + residual, LN2, transposed store ---
  #pragma unroll
  for (int d = 0; d < 64; ++d) z[d] += bf2[d] + y[d];
  float mu2, rs2;
  {
    float m0 = 0.f, m1 = 0.f, m2 = 0.f, m3 = 0.f;
    #pragma unroll
    for (int j = 0; j < 16; ++j) {
      m0 += z[4 * j + 0]; m1 += z[4 * j + 1]; m2 += z[4 * j + 2]; m3 += z[4 * j + 3];
    }
    mu2 = ((m0 + m1) + (m2 + m3)) * (1.f / 64.f);
    float v0 = 0.f, v1 = 0.f, v2 = 0.f, v3 = 0.f;
    #pragma unroll
    for (int j = 0; j < 16; ++j) {
      float t0 = z[4 * j + 0] - mu2, t1 = z[4 * j + 1] - mu2;
      float t2 = z[4 * j + 2] - mu2, t3 = z[4 * j + 3] - mu2;
      v0 = fmaf(t0, t0, v0); v1 = fmaf(t1, t1, v1);
      v2 = fmaf(t2, t2, v2); v3 = fmaf(t3, t3, v3);
    }
    float var2 = ((v0 + v1) + (v2 + v3)) * (1.f / 64.f);
    rs2 = rsqrtf(var2 + 1e-5f);
  }
  float4* op = reinterpret_cast<float4*>(out + ((size_t)s * NT + t) * DIM);
  #pragma unroll
  for (int i = 0; i < 16; ++i) {
    op[i] = make_float4(
        (z[4 * i + 0] - mu2) * rs2 * g2[4 * i + 0] + be2[4 * i + 0],
        (z[4 * i + 1] - mu2) * rs2 * g2[4 * i + 1] + be2[4 * i + 1],
        (z[4 * i + 2] - mu2) * rs2 * g2[4 * i + 2] + be2[4 * i + 2],
        (z[4 * i + 3] - mu2) * rs2 * g2[4 * i + 3] + be2[4 * i + 3]);
  }
}

extern "C" void kernel_launch(void* const* d_in, const int* in_sizes, int n_in,
                              void* d_out, int out_size, void* d_ws, size_t ws_size,
                              hipStream_t stream) {
  const float* x    = (const float*)d_in[0];
  const float* Wqkv = (const float*)d_in[1];
  const float* bqkv = (const float*)d_in[2];
  const float* Wo   = (const float*)d_in[3];
  const float* bo   = (const float*)d_in[4];
  const float* g1   = (const float*)d_in[5];
  const float* be1  = (const float*)d_in[6];
  const float* W1   = (const float*)d_in[7];
  const float* bf1  = (const float*)d_in[8];
  const float* W2   = (const float*)d_in[9];
  const float* bf2  = (const float*)d_in[10];
  const float* g2   = (const float*)d_in[11];
  const float* be2  = (const float*)d_in[12];
  float* out = (float*)d_out;

  // ws layout: [0, 64KB) W2T  |  [64KB, 64KB + 64MB) V rows -> then ctx
  float* W2T  = (float*)d_ws;
  float* vbuf = (float*)((char*)d_ws + 65536);

  hipLaunchKernelGGL(k_transpose_w2, dim3(64), dim3(256), 0, stream, W2, W2T);
  hipLaunchKernelGGL(k_attn, dim3(NT, 2), dim3(512), 65536, stream, x, Wqkv, bqkv, vbuf);
  hipLaunchKernelGGL(k_tail, dim3(1024), dim3(256), 65536, stream,
                     vbuf, x, Wo, bo, g1, be1, W1, bf1, W2T, bf2, g2, be2, out);
}

// Round 2
// 1082.744 us; speedup vs baseline: 1.8510x; 1.8510x over previous
//
#include <hip/hip_runtime.h>
#include <hip/hip_bf16.h>
#include <cmath>

#define NS 512   // n_stocks (sequence length of the attention)
#define NT 512   // tau (batch)
#define DIM 64
#define HD 32

typedef __attribute__((ext_vector_type(8))) short short8;    // 8 bf16 = 4 VGPR
typedef __attribute__((ext_vector_type(16))) float f32x16;   // MFMA 32x32 acc

union FragU { unsigned w[4]; short8 f; };

__device__ __forceinline__ unsigned short bfbits(float x) {
  __hip_bfloat16 h = __float2bfloat16(x);
  return __builtin_bit_cast(unsigned short, h);
}
__device__ __forceinline__ unsigned pk2(float lo, float hi) {
  return (unsigned)bfbits(lo) | ((unsigned)bfbits(hi) << 16);
}

// 4-way-split dot product over 64 elements (breaks the 4-cyc FMA dep chain).
__device__ __forceinline__ float dot64(const float* __restrict__ w, const float* xr) {
  float a0 = 0.f, a1 = 0.f, a2 = 0.f, a3 = 0.f;
  #pragma unroll
  for (int j = 0; j < 16; ++j) {
    a0 = fmaf(w[4 * j + 0], xr[4 * j + 0], a0);
    a1 = fmaf(w[4 * j + 1], xr[4 * j + 1], a1);
    a2 = fmaf(w[4 * j + 2], xr[4 * j + 2], a2);
    a3 = fmaf(w[4 * j + 3], xr[4 * j + 3], a3);
  }
  return (a0 + a1) + (a2 + a3);
}

// ---------------- K0: transpose W2 (64x256) -> W2T (256x64) ----------------
__global__ void k_transpose_w2(const float* __restrict__ W2, float* __restrict__ W2T) {
  int idx = blockIdx.x * 256 + threadIdx.x;  // 16384 elements
  int d = idx >> 8;
  int j = idx & 255;
  W2T[j * 64 + d] = W2[d * 256 + j];
}

// ---------------- K1: fused QKV + MFMA attention, one block per (t, h) -----
// 512 threads = 8 waves; wave w owns query rows [w*64, w*64+64).
// Projection: per-thread fp32 VALU (thread s = stock s), results stored bf16:
//   K -> LDS [512][32] (64B pitch, chunk^(row&3) swizzle)
//   V -> LDS transposed Vt[32][512] (1024B pitch, chunk^(d&7) swizzle)
//   Q -> registers, fragments assembled via in-wave shuffles.
// Attention: S^T tile = mfma(K_tile, Q^T) so softmax is lane-local (q=lane&31);
// no running max (exp can't overflow at these magnitudes; softmax is
// shift-invariant); P repacked to A-fragments via cvt_pk pairs + shfl_xor(32).
__global__ __launch_bounds__(512) void k_attn(
    const float* __restrict__ x, const float* __restrict__ Wqkv,
    const float* __restrict__ bqkv, float* __restrict__ ctx) {
  extern __shared__ char smem[];          // 64 KB: K 32KB | Vt 32KB
  char* Ksm = smem;
  char* Vsm = smem + 32768;
  const int t = blockIdx.x, h = blockIdx.y;
  const int tid = threadIdx.x;
  const int l   = tid & 63;
  const int wv  = tid >> 6;
  const int hi  = l >> 5;
  const int l31 = l & 31;

  // ---------- projection: thread s computes q,k,v for stock s ----------
  const int s = tid;
  float xr[64];
  {
    const float4* xp = reinterpret_cast<const float4*>(x + ((size_t)s * NT + t) * DIM);
    #pragma unroll
    for (int i = 0; i < 16; ++i) {
      float4 v = xp[i];
      xr[4 * i + 0] = v.x; xr[4 * i + 1] = v.y;
      xr[4 * i + 2] = v.z; xr[4 * i + 3] = v.w;
    }
  }

  // q (scale 1/sqrt(32) folded) -> 16 packed bf16 pairs in registers
  unsigned qpk[16];
  {
    const float* wq = Wqkv + (size_t)(h * HD) * DIM;
    const float* bq = bqkv + h * HD;
    #pragma unroll
    for (int w = 0; w < 16; ++w) {
      float a = (dot64(wq + (2 * w) * DIM, xr) + bq[2 * w]) * 0.17677669529663687f;
      float b = (dot64(wq + (2 * w + 1) * DIM, xr) + bq[2 * w + 1]) * 0.17677669529663687f;
      qpk[w] = pk2(a, b);
    }
  }

  // k -> LDS rows (64B pitch), 16B chunks XOR-swizzled by (row&3)
  {
    const float* wk = Wqkv + (size_t)(64 + h * HD) * DIM;
    const float* bk = bqkv + 64 + h * HD;
    #pragma clang loop unroll(disable)
    for (int c2 = 0; c2 < 4; ++c2) {
      float kc[8];
      #pragma unroll
      for (int u = 0; u < 8; ++u) kc[u] = dot64(wk + (c2 * 8 + u) * DIM, xr) + bk[c2 * 8 + u];
      FragU fu;
      fu.w[0] = pk2(kc[0], kc[1]); fu.w[1] = pk2(kc[2], kc[3]);
      fu.w[2] = pk2(kc[4], kc[5]); fu.w[3] = pk2(kc[6], kc[7]);
      *reinterpret_cast<short8*>(Ksm + s * 64 + ((c2 ^ (s & 3)) << 4)) = fu.f;
    }
  }

  // v -> LDS transposed Vt[d][key] (1024B pitch), chunks XOR-swizzled by (d&7)
  {
    const float* wvp = Wqkv + (size_t)(128 + h * HD) * DIM;
    const float* bv  = bqkv + 128 + h * HD;
    #pragma clang loop unroll(disable)
    for (int c = 0; c < 4; ++c) {
      float vc[8];
      #pragma unroll
      for (int u = 0; u < 8; ++u) vc[u] = dot64(wvp + (c * 8 + u) * DIM, xr) + bv[c * 8 + u];
      #pragma unroll
      for (int u = 0; u < 8; ++u) {
        int d = c * 8 + u;
        *reinterpret_cast<unsigned short*>(
            Vsm + d * 1024 + (((s >> 3) ^ (d & 7)) << 4) + ((s & 7) << 1)) = bfbits(vc[u]);
      }
    }
  }

  // Q fragments: wave w's queries are its own lanes -> in-wave shuffles.
  // B-layout for mfma_32x32x16: lane holds B[k=(l>>5)*8+j][col=l&31].
  short8 qfrag[2][2];
  #pragma unroll
  for (int sb = 0; sb < 2; ++sb) {
    int srcl = sb * 32 + l31;
    #pragma unroll
    for (int dc = 0; dc < 2; ++dc) {
      unsigned tw[8];
      #pragma unroll
      for (int j = 0; j < 8; ++j) tw[j] = (unsigned)__shfl((int)qpk[dc * 8 + j], srcl, 64);
      FragU fu;
      fu.w[0] = hi ? tw[4] : tw[0];
      fu.w[1] = hi ? tw[5] : tw[1];
      fu.w[2] = hi ? tw[6] : tw[2];
      fu.w[3] = hi ? tw[7] : tw[3];
      qfrag[sb][dc] = fu.f;
    }
  }

  __syncthreads();

  // ---------- attention main loop over 16 key tiles of 32 ----------
  f32x16 oacc[2];
  #pragma unroll
  for (int i = 0; i < 16; ++i) { oacc[0][i] = 0.f; oacc[1][i] = 0.f; }
  float lsum[2] = {0.f, 0.f};

  #pragma clang loop unroll(disable)
  for (int kt = 0; kt < 16; ++kt) {
    short8 kfrag[2], vfrag[2];
    #pragma unroll
    for (int dc = 0; dc < 2; ++dc) {
      int row = kt * 32 + l31;
      kfrag[dc] = *reinterpret_cast<const short8*>(
          Ksm + row * 64 + ((((dc << 1) | hi) ^ (l31 & 3)) << 4));
    }
    #pragma unroll
    for (int c = 0; c < 2; ++c) {
      int ck = kt * 4 + (c << 1) + hi;
      vfrag[c] = *reinterpret_cast<const short8*>(
          Vsm + l31 * 1024 + ((ck ^ (l31 & 7)) << 4));
    }
    #pragma unroll
    for (int sb = 0; sb < 2; ++sb) {
      // S^T tile: rows = keys, cols = queries (q = lane&31)
      f32x16 st = {};
      st = __builtin_amdgcn_mfma_f32_32x32x16_bf16(kfrag[0], qfrag[sb][0], st, 0, 0, 0);
      st = __builtin_amdgcn_mfma_f32_32x32x16_bf16(kfrag[1], qfrag[sb][1], st, 0, 0, 0);
      // lane-local exp + row-sum; reg r holds key (r&3)+8*(r>>2)+4*hi
      float p[16];
      #pragma unroll
      for (int r = 0; r < 16; ++r) { p[r] = __expf(st[r]); lsum[sb] += p[r]; }
      // pack to bf16 pairs, swap halves across lane^32, assemble A-fragments
      unsigned pk[8], xk[8];
      #pragma unroll
      for (int j = 0; j < 8; ++j) pk[j] = pk2(p[2 * j], p[2 * j + 1]);
      #pragma unroll
      for (int j = 0; j < 8; ++j) xk[j] = (unsigned)__shfl_xor((int)pk[j], 32, 64);
      FragU a1, a2;
      a1.w[0] = hi ? xk[2] : pk[0];
      a1.w[1] = hi ? xk[3] : pk[1];
      a1.w[2] = hi ? pk[2] : xk[0];
      a1.w[3] = hi ? pk[3] : xk[1];
      a2.w[0] = hi ? xk[6] : pk[4];
      a2.w[1] = hi ? xk[7] : pk[5];
      a2.w[2] = hi ? pk[6] : xk[4];
      a2.w[3] = hi ? pk[7] : xk[5];
      oacc[sb] = __builtin_amdgcn_mfma_f32_32x32x16_bf16(a1.f, vfrag[0], oacc[sb], 0, 0, 0);
      oacc[sb] = __builtin_amdgcn_mfma_f32_32x32x16_bf16(a2.f, vfrag[1], oacc[sb], 0, 0, 0);
    }
  }

  // ---------- normalize + store ctx ----------
  #pragma unroll
  for (int sb = 0; sb < 2; ++sb) {
    float lt = lsum[sb] + __shfl_xor(lsum[sb], 32, 64);
    float inv = 1.f / lt;
    float* cb = ctx + ((size_t)(t * 2 + h) * NS + (size_t)wv * 64 + (size_t)sb * 32) * HD + l31;
    #pragma unroll
    for (int r = 0; r < 16; ++r) {
      int ql = (r & 3) + 8 * (r >> 2) + 4 * hi;
      float fac = __shfl(inv, ql, 64);
      cb[ql * HD] = oacc[sb][r] * fac;
    }
  }
}

// ---------------- K2: fused Wo-proj + LN1 + FFN + LN2 + transpose ----------
__global__ __launch_bounds__(256) void k_tail(
    const float* __restrict__ cbuf,   // ctx, layout (t, h, s, 32)
    const float* __restrict__ x,
    const float* __restrict__ Wo, const float* __restrict__ bo,
    const float* __restrict__ g1, const float* __restrict__ be1,
    const float* __restrict__ W1, const float* __restrict__ bf1,
    const float* __restrict__ W2T, const float* __restrict__ bf2,
    const float* __restrict__ g2, const float* __restrict__ be2,
    float* __restrict__ out) {
  extern __shared__ float aout[];  // [64][256] = 64 KB, column per thread
  const int tid = threadIdx.x;
  const size_t r = (size_t)blockIdx.x * 256 + tid;
  const int t = (int)(r >> 9), s = (int)(r & 511);

  float c[64];
  {
    const float4* p0 = reinterpret_cast<const float4*>(cbuf + ((size_t)(t * 2 + 0) * NS + s) * HD);
    const float4* p1 = reinterpret_cast<const float4*>(cbuf + ((size_t)(t * 2 + 1) * NS + s) * HD);
    #pragma unroll
    for (int i = 0; i < 8; ++i) {
      float4 v = p0[i];
      c[4 * i + 0] = v.x; c[4 * i + 1] = v.y; c[4 * i + 2] = v.z; c[4 * i + 3] = v.w;
    }
    #pragma unroll
    for (int i = 0; i < 8; ++i) {
      float4 v = p1[i];
      c[32 + 4 * i + 0] = v.x; c[32 + 4 * i + 1] = v.y;
      c[32 + 4 * i + 2] = v.z; c[32 + 4 * i + 3] = v.w;
    }
  }

  #pragma clang loop unroll(disable)
  for (int d = 0; d < 64; ++d) {
    aout[d * 256 + tid] = dot64(Wo + d * 64, c) + bo[d];
  }

  float y[64];
  {
    const float4* xp = reinterpret_cast<const float4*>(x + ((size_t)s * NT + t) * DIM);
    #pragma unroll
    for (int i = 0; i < 16; ++i) {
      float4 v = xp[i];
      y[4 * i + 0] = v.x + aout[(4 * i + 0) * 256 + tid];
      y[4 * i + 1] = v.y + aout[(4 * i + 1) * 256 + tid];
      y[4 * i + 2] = v.z + aout[(4 * i + 2) * 256 + tid];
      y[4 * i + 3] = v.w + aout[(4 * i + 3) * 256 + tid];
    }
  }
  {
    float m0 = 0.f, m1 = 0.f, m2 = 0.f, m3 = 0.f;
    #pragma unroll
    for (int j = 0; j < 16; ++j) {
      m0 += y[4 * j + 0]; m1 += y[4 * j + 1]; m2 += y[4 * j + 2]; m3 += y[4 * j + 3];
    }
    float mu = ((m0 + m1) + (m2 + m3)) * (1.f / 64.f);
    float v0 = 0.f, v1 = 0.f, v2 = 0.f, v3 = 0.f;
    #pragma unroll
    for (int j = 0; j < 16; ++j) {
      float t0 = y[4 * j + 0] - mu, t1 = y[4 * j + 1] - mu;
      float t2 = y[4 * j + 2] - mu, t3 = y[4 * j + 3] - mu;
      v0 = fmaf(t0, t0, v0); v1 = fmaf(t1, t1, v1);
      v2 = fmaf(t2, t2, v2); v3 = fmaf(t3, t3, v3);
    }
    float var = ((v0 + v1) + (v2 + v3)) * (1.f / 64.f);
    float rs = rsqrtf(var + 1e-5f);
    #pragma unroll
    for (int d = 0; d < 64; ++d) y[d] = (y[d] - mu) * rs * g1[d] + be1[d];
  }

  float z[64];
  #pragma unroll
  for (int d = 0; d < 64; ++d) z[d] = 0.f;
  #pragma clang loop unroll_count(2)
  for (int j = 0; j < 256; ++j) {
    float a = dot64(W1 + j * 64, y) + bf1[j];
    a = fmaxf(a, 0.f);
    const float* w2r = W2T + j * 64;
    #pragma unroll
    for (int d = 0; d < 64; ++d) z[d] = fmaf(w2r[d], a, z[d]);
  }

  #pragma unroll
  for (int d = 0; d < 64; ++d) z[d] += bf2[d] + y[d];
  float mu2, rs2;
  {
    float m0 = 0.f, m1 = 0.f, m2 = 0.f, m3 = 0.f;
    #pragma unroll
    for (int j = 0; j < 16; ++j) {
      m0 += z[4 * j + 0]; m1 += z[4 * j + 1]; m2 += z[4 * j + 2]; m3 += z[4 * j + 3];
    }
    mu2 = ((m0 + m1) + (m2 + m3)) * (1.f / 64.f);
    float v0 = 0.f, v1 = 0.f, v2 = 0.f, v3 = 0.f;
    #pragma unroll
    for (int j = 0; j < 16; ++j) {
      float t0 = z[4 * j + 0] - mu2, t1 = z[4 * j + 1] - mu2;
      float t2 = z[4 * j + 2] - mu2, t3 = z[4 * j + 3] - mu2;
      v0 = fmaf(t0, t0, v0); v1 = fmaf(t1, t1, v1);
      v2 = fmaf(t2, t2, v2); v3 = fmaf(t3, t3, v3);
    }
    float var2 = ((v0 + v1) + (v2 + v3)) * (1.f / 64.f);
    rs2 = rsqrtf(var2 + 1e-5f);
  }
  float4* op = reinterpret_cast<float4*>(out + ((size_t)s * NT + t) * DIM);
  #pragma unroll
  for (int i = 0; i < 16; ++i) {
    op[i] = make_float4(
        (z[4 * i + 0] - mu2) * rs2 * g2[4 * i + 0] + be2[4 * i + 0],
        (z[4 * i + 1] - mu2) * rs2 * g2[4 * i + 1] + be2[4 * i + 1],
        (z[4 * i + 2] - mu2) * rs2 * g2[4 * i + 2] + be2[4 * i + 2],
        (z[4 * i + 3] - mu2) * rs2 * g2[4 * i + 3] + be2[4 * i + 3]);
  }
}

extern "C" void kernel_launch(void* const* d_in, const int* in_sizes, int n_in,
                              void* d_out, int out_size, void* d_ws, size_t ws_size,
                              hipStream_t stream) {
  const float* x    = (const float*)d_in[0];
  const float* Wqkv = (const float*)d_in[1];
  const float* bqkv = (const float*)d_in[2];
  const float* Wo   = (const float*)d_in[3];
  const float* bo   = (const float*)d_in[4];
  const float* g1   = (const float*)d_in[5];
  const float* be1  = (const float*)d_in[6];
  const float* W1   = (const float*)d_in[7];
  const float* bf1  = (const float*)d_in[8];
  const float* W2   = (const float*)d_in[9];
  const float* bf2  = (const float*)d_in[10];
  const float* g2   = (const float*)d_in[11];
  const float* be2  = (const float*)d_in[12];
  float* out = (float*)d_out;

  // ws layout: [0, 64KB) W2T  |  [64KB, 64KB + 64MB) ctx
  float* W2T  = (float*)d_ws;
  float* cbuf = (float*)((char*)d_ws + 65536);

  hipLaunchKernelGGL(k_transpose_w2, dim3(64), dim3(256), 0, stream, W2, W2T);
  hipLaunchKernelGGL(k_attn, dim3(NT, 2), dim3(512), 65536, stream, x, Wqkv, bqkv, cbuf);
  hipLaunchKernelGGL(k_tail, dim3(1024), dim3(256), 65536, stream,
                     cbuf, x, Wo, bo, g1, be1, W1, bf1, W2T, bf2, g2, be2, out);
}

// Round 3
// 173.852 us; speedup vs baseline: 11.5277x; 6.2280x over previous
//
#include <hip/hip_runtime.h>
#include <hip/hip_bf16.h>
#include <cmath>

#define NS 512   // n_stocks (attention sequence length)
#define NT 512   // tau (batch)
#define DIM 64
#define HD 32

typedef __attribute__((ext_vector_type(8))) short short8;    // 8 bf16 = 4 VGPR
typedef __attribute__((ext_vector_type(16))) float f32x16;   // MFMA 32x32 acc

union FragU { unsigned w[4]; short8 f; };

__device__ __forceinline__ unsigned short bfbits(float x) {
  __hip_bfloat16 h = __float2bfloat16(x);
  return __builtin_bit_cast(unsigned short, h);
}
__device__ __forceinline__ unsigned pk2(float lo, float hi) {
  return (unsigned)bfbits(lo) | ((unsigned)bfbits(hi) << 16);
}
__device__ __forceinline__ float lo_f(unsigned w) { return __uint_as_float(w << 16); }
__device__ __forceinline__ float hi_f(unsigned w) { return __uint_as_float(w & 0xffff0000u); }
__device__ __forceinline__ short8 ldg8(const __hip_bfloat16* p) {
  return *reinterpret_cast<const short8*>(p);
}

// Repack a 32x32 C-frag (col=l31 fixed, row=(r&3)+8*(r>>2)+4*hi) into two
// A/B-frags along k (o1: k=0..15, o2: k=16..31). Validated in round 2.
__device__ __forceinline__ void repack(const float* p, int hi, short8& o1, short8& o2) {
  unsigned pk[8], xk[8];
  #pragma unroll
  for (int j = 0; j < 8; ++j) pk[j] = pk2(p[2 * j], p[2 * j + 1]);
  #pragma unroll
  for (int j = 0; j < 8; ++j) xk[j] = (unsigned)__shfl_xor((int)pk[j], 32, 64);
  FragU a1, a2;
  a1.w[0] = hi ? xk[2] : pk[0];
  a1.w[1] = hi ? xk[3] : pk[1];
  a1.w[2] = hi ? pk[2] : xk[0];
  a1.w[3] = hi ? pk[3] : xk[1];
  a2.w[0] = hi ? xk[6] : pk[4];
  a2.w[1] = hi ? xk[7] : pk[5];
  a2.w[2] = hi ? pk[6] : xk[4];
  a2.w[3] = hi ? pk[7] : xk[5];
  o1 = a1.f; o2 = a2.f;
}

// ---------------- K0: convert all weights fp32 -> bf16 in ws ----------------
// layout (elements): Wqkv @0 (12288) | Wo @12288 (4096) | W1 @16384 (16384) | W2 @32768 (16384)
__global__ void k_cvt(const float* __restrict__ Wqkv, const float* __restrict__ Wo,
                      const float* __restrict__ W1, const float* __restrict__ W2,
                      __hip_bfloat16* __restrict__ dst) {
  int i = blockIdx.x * 256 + threadIdx.x;  // 49152 total
  float v;
  if (i < 12288) v = Wqkv[i];
  else if (i < 16384) v = Wo[i - 12288];
  else if (i < 32768) v = W1[i - 16384];
  else v = W2[i - 32768];
  dst[i] = __float2bfloat16(v);
}

// ---------------- K1: MFMA QKV projection + MFMA attention -----------------
// One block per (t, h), 512 threads = 8 waves; wave w owns stocks/queries
// [64w, 64w+64). LDS 64KB: phase A = Xsm[512][64bf16]; after barrier reused as
// Ksm[512 keys][32 kd] (pitch 64B, chunk^(key&3)) at [0,32K) and
// Vt[32 vd][512 keys] (pitch 1024B, chunk^(vd&7)) at [32K,64K).
__global__ __launch_bounds__(512, 4) void k_attn(
    const float* __restrict__ x, const __hip_bfloat16* __restrict__ Wb,
    const float* __restrict__ bqkv, __hip_bfloat16* __restrict__ ctx) {
  __shared__ char smem[65536];
  const int t = blockIdx.x, h = blockIdx.y;
  const int tid = threadIdx.x;
  const int l = tid & 63, wv = tid >> 6, hi = l >> 5, l31 = l & 31;

  // ---- load x row (stock = tid), pack bf16, stage to Xsm ----
  {
    const float4* xp = reinterpret_cast<const float4*>(x + ((size_t)tid * NT + t) * DIM);
    unsigned xpk[32];
    #pragma unroll
    for (int i = 0; i < 16; ++i) {
      float4 v = xp[i];
      xpk[2 * i]     = pk2(v.x, v.y);
      xpk[2 * i + 1] = pk2(v.z, v.w);
    }
    #pragma unroll
    for (int c = 0; c < 8; ++c) {
      FragU fu;
      fu.w[0] = xpk[4*c]; fu.w[1] = xpk[4*c+1]; fu.w[2] = xpk[4*c+2]; fu.w[3] = xpk[4*c+3];
      *reinterpret_cast<short8*>(smem + tid * 128 + ((c ^ (tid & 7)) << 4)) = fu.f;
    }
  }
  __syncthreads();

  // ---- read x fragments (A for K/V proj; identical layout = B for Q^T proj)
  short8 xf[2][4];
  #pragma unroll
  for (int rt = 0; rt < 2; ++rt) {
    int row = wv * 64 + rt * 32 + l31;
    #pragma unroll
    for (int st = 0; st < 4; ++st)
      xf[rt][st] = *reinterpret_cast<const short8*>(
          smem + row * 128 + ((((st << 1) | hi) ^ (row & 7)) << 4));
  }
  __syncthreads();  // drains reads; Xsm region now reusable for Ksm/Vt

  // ---- Q^T projection -> qfrag (registers only) ----
  short8 qfrag[2][2];
  {
    short8 wqa[4];
    #pragma unroll
    for (int st = 0; st < 4; ++st)
      wqa[st] = ldg8(Wb + (size_t)(h * 32 + l31) * 64 + st * 16 + hi * 8);
    float bqv[16];
    #pragma unroll
    for (int r = 0; r < 16; ++r)
      bqv[r] = bqkv[h * 32 + (r & 3) + 8 * (r >> 2) + 4 * hi];
    #pragma unroll
    for (int rt = 0; rt < 2; ++rt) {
      f32x16 qa = {};
      #pragma unroll
      for (int st = 0; st < 4; ++st)
        qa = __builtin_amdgcn_mfma_f32_32x32x16_bf16(wqa[st], xf[rt][st], qa, 0, 0, 0);
      float p[16];
      #pragma unroll
      for (int r = 0; r < 16; ++r) p[r] = (qa[r] + bqv[r]) * 0.17677669529663687f;
      repack(p, hi, qfrag[rt][0], qfrag[rt][1]);
    }
  }

  // ---- K projection -> Ksm ----
  {
    short8 wkb[4];
    #pragma unroll
    for (int st = 0; st < 4; ++st)
      wkb[st] = ldg8(Wb + (size_t)(64 + h * 32 + l31) * 64 + st * 16 + hi * 8);
    float bk = bqkv[64 + h * 32 + l31];
    #pragma unroll
    for (int rt = 0; rt < 2; ++rt) {
      f32x16 ka = {};
      #pragma unroll
      for (int st = 0; st < 4; ++st)
        ka = __builtin_amdgcn_mfma_f32_32x32x16_bf16(xf[rt][st], wkb[st], ka, 0, 0, 0);
      #pragma unroll
      for (int r = 0; r < 16; ++r) {
        int key = wv * 64 + rt * 32 + (r & 3) + 8 * (r >> 2) + 4 * hi;
        *reinterpret_cast<unsigned short*>(
            smem + key * 64 + (((l31 >> 3) ^ (key & 3)) << 4) + ((l31 & 7) << 1)) =
            bfbits(ka[r] + bk);
      }
    }
  }

  // ---- V projection -> Vt ----
  {
    short8 wvb[4];
    #pragma unroll
    for (int st = 0; st < 4; ++st)
      wvb[st] = ldg8(Wb + (size_t)(128 + h * 32 + l31) * 64 + st * 16 + hi * 8);
    float bv = bqkv[128 + h * 32 + l31];
    #pragma unroll
    for (int rt = 0; rt < 2; ++rt) {
      f32x16 va = {};
      #pragma unroll
      for (int st = 0; st < 4; ++st)
        va = __builtin_amdgcn_mfma_f32_32x32x16_bf16(xf[rt][st], wvb[st], va, 0, 0, 0);
      #pragma unroll
      for (int g = 0; g < 4; ++g) {
        int kb = wv * 64 + rt * 32 + g * 8 + hi * 4;
        uint2 d2 = make_uint2(pk2(va[4*g] + bv, va[4*g+1] + bv),
                              pk2(va[4*g+2] + bv, va[4*g+3] + bv));
        *reinterpret_cast<uint2*>(
            smem + 32768 + l31 * 1024 + ((((kb >> 3) ^ (l31 & 7)) << 4) + ((kb & 7) << 1))) = d2;
      }
    }
  }
  __syncthreads();

  // ---- attention main loop (validated round-2 machinery) ----
  f32x16 oacc[2];
  #pragma unroll
  for (int i = 0; i < 16; ++i) { oacc[0][i] = 0.f; oacc[1][i] = 0.f; }
  float lsum[2] = {0.f, 0.f};

  #pragma clang loop unroll(disable)
  for (int kt = 0; kt < 16; ++kt) {
    short8 kfrag[2], vfrag[2];
    #pragma unroll
    for (int dc = 0; dc < 2; ++dc) {
      int row = kt * 32 + l31;
      kfrag[dc] = *reinterpret_cast<const short8*>(
          smem + row * 64 + ((((dc << 1) | hi) ^ (l31 & 3)) << 4));
    }
    #pragma unroll
    for (int c = 0; c < 2; ++c) {
      int ck = kt * 4 + (c << 1) + hi;
      vfrag[c] = *reinterpret_cast<const short8*>(
          smem + 32768 + l31 * 1024 + ((ck ^ (l31 & 7)) << 4));
    }
    #pragma unroll
    for (int sb = 0; sb < 2; ++sb) {
      f32x16 st = {};
      st = __builtin_amdgcn_mfma_f32_32x32x16_bf16(kfrag[0], qfrag[sb][0], st, 0, 0, 0);
      st = __builtin_amdgcn_mfma_f32_32x32x16_bf16(kfrag[1], qfrag[sb][1], st, 0, 0, 0);
      float p[16];
      #pragma unroll
      for (int r = 0; r < 16; ++r) { p[r] = __expf(st[r]); lsum[sb] += p[r]; }
      short8 a1, a2;
      repack(p, hi, a1, a2);
      oacc[sb] = __builtin_amdgcn_mfma_f32_32x32x16_bf16(a1, vfrag[0], oacc[sb], 0, 0, 0);
      oacc[sb] = __builtin_amdgcn_mfma_f32_32x32x16_bf16(a2, vfrag[1], oacc[sb], 0, 0, 0);
    }
  }

  // ---- normalize + store ctx (bf16, [t][s][64] layout) ----
  #pragma unroll
  for (int sb = 0; sb < 2; ++sb) {
    float lt = lsum[sb] + __shfl_xor(lsum[sb], 32, 64);
    float inv = 1.f / lt;
    #pragma unroll
    for (int r = 0; r < 16; ++r) {
      int ql = (r & 3) + 8 * (r >> 2) + 4 * hi;
      float fac = __shfl(inv, ql, 64);
      int q = wv * 64 + sb * 32 + ql;
      ctx[((size_t)t * 512 + q) * 64 + h * 32 + l31] = __float2bfloat16(oacc[sb][r] * fac);
    }
  }
}

// ---------------- K2: MFMA Wo + LN1 + MFMA FFN + LN2 ----------------
// One block per t, 512 threads = 8 waves; wave w owns rows [64w, 64w+64).
// LDS: R1 [0,64K) ctx->aout^T->z^T (bf16 [512][64], pitch 128B, chunk^(s&7));
//      R2 [64K,128K) y (same geometry); params @128K (640 floats).
__global__ __launch_bounds__(512, 2) void k_tail(
    const __hip_bfloat16* __restrict__ ctx, const float* __restrict__ x,
    const __hip_bfloat16* __restrict__ Wob, const float* __restrict__ bo,
    const float* __restrict__ g1, const float* __restrict__ be1,
    const __hip_bfloat16* __restrict__ W1b, const float* __restrict__ bf1,
    const __hip_bfloat16* __restrict__ W2b, const float* __restrict__ bf2,
    const float* __restrict__ g2, const float* __restrict__ be2,
    float* __restrict__ out) {
  __shared__ char sm[133632];
  float* ps = reinterpret_cast<float*>(sm + 131072);
  const int t = blockIdx.x;
  const int tid = threadIdx.x;
  const int l = tid & 63, wv = tid >> 6, hi = l >> 5, l31 = l & 31;

  // ---- stage ctx row + params ----
  {
    const short8* cp = reinterpret_cast<const short8*>(ctx + ((size_t)t * 512 + tid) * 64);
    #pragma unroll
    for (int c = 0; c < 8; ++c)
      *reinterpret_cast<short8*>(sm + tid * 128 + ((c ^ (tid & 7)) << 4)) = cp[c];
  }
  for (int i = tid; i < 640; i += 512) {
    float v;
    if (i < 64) v = g1[i];
    else if (i < 128) v = be1[i - 64];
    else if (i < 192) v = bo[i - 128];
    else if (i < 256) v = bf2[i - 192];
    else if (i < 320) v = g2[i - 256];
    else if (i < 384) v = be2[i - 320];
    else v = bf1[i - 384];
    ps[i] = v;
  }
  __syncthreads();

  // ---- phase 1: aout^T = Wo @ ctx^T (per wave, own rows), scatter to R1 ----
  {
    short8 cb[2][4];
    #pragma unroll
    for (int stl = 0; stl < 2; ++stl) {
      int row = wv * 64 + stl * 32 + l31;
      #pragma unroll
      for (int st = 0; st < 4; ++st)
        cb[stl][st] = *reinterpret_cast<const short8*>(
            sm + row * 128 + ((((st << 1) | hi) ^ (row & 7)) << 4));
    }
    f32x16 ao[2][2];
    #pragma unroll
    for (int dt = 0; dt < 2; ++dt) {
      short8 wa[4];
      #pragma unroll
      for (int st = 0; st < 4; ++st)
        wa[st] = ldg8(Wob + (size_t)(dt * 32 + l31) * 64 + st * 16 + hi * 8);
      #pragma unroll
      for (int stl = 0; stl < 2; ++stl) {
        f32x16 a = {};
        #pragma unroll
        for (int st = 0; st < 4; ++st)
          a = __builtin_amdgcn_mfma_f32_32x32x16_bf16(wa[st], cb[stl][st], a, 0, 0, 0);
        ao[dt][stl] = a;
      }
    }
    #pragma unroll
    for (int dt = 0; dt < 2; ++dt)
      #pragma unroll
      for (int stl = 0; stl < 2; ++stl) {
        int s_ = wv * 64 + stl * 32 + l31;
        #pragma unroll
        for (int rp = 0; rp < 8; ++rp) {
          int r = 2 * rp;
          int d = dt * 32 + (r & 3) + 8 * (r >> 2) + 4 * hi;
          *reinterpret_cast<unsigned*>(
              sm + s_ * 128 + (((d >> 3) ^ (s_ & 7)) << 4) + ((d & 7) << 1)) =
              pk2(ao[dt][stl][r], ao[dt][stl][r + 1]);
        }
      }
  }
  __syncthreads();

  // ---- phase 2: per-thread row: y = LN1(x + aout + bo), write y -> R2 ----
  float y[64];
  {
    float aov[64];
    #pragma unroll
    for (int c = 0; c < 8; ++c) {
      FragU fu;
      fu.f = *reinterpret_cast<const short8*>(sm + tid * 128 + ((c ^ (tid & 7)) << 4));
      #pragma unroll
      for (int u = 0; u < 4; ++u) {
        aov[c * 8 + 2 * u]     = lo_f(fu.w[u]);
        aov[c * 8 + 2 * u + 1] = hi_f(fu.w[u]);
      }
    }
    const float4* xp = reinterpret_cast<const float4*>(x + ((size_t)tid * NT + t) * DIM);
    #pragma unroll
    for (int i = 0; i < 16; ++i) {
      float4 v = xp[i];
      y[4*i+0] = v.x + aov[4*i+0] + ps[128 + 4*i+0];
      y[4*i+1] = v.y + aov[4*i+1] + ps[128 + 4*i+1];
      y[4*i+2] = v.z + aov[4*i+2] + ps[128 + 4*i+2];
      y[4*i+3] = v.w + aov[4*i+3] + ps[128 + 4*i+3];
    }
    float m0 = 0.f, m1 = 0.f, m2 = 0.f, m3 = 0.f;
    #pragma unroll
    for (int j = 0; j < 16; ++j) {
      m0 += y[4*j+0]; m1 += y[4*j+1]; m2 += y[4*j+2]; m3 += y[4*j+3];
    }
    float mu = ((m0 + m1) + (m2 + m3)) * (1.f / 64.f);
    float v0 = 0.f, v1 = 0.f, v2 = 0.f, v3 = 0.f;
    #pragma unroll
    for (int j = 0; j < 16; ++j) {
      float t0 = y[4*j+0] - mu, t1 = y[4*j+1] - mu;
      float t2 = y[4*j+2] - mu, t3 = y[4*j+3] - mu;
      v0 = fmaf(t0, t0, v0); v1 = fmaf(t1, t1, v1);
      v2 = fmaf(t2, t2, v2); v3 = fmaf(t3, t3, v3);
    }
    float var = ((v0 + v1) + (v2 + v3)) * (1.f / 64.f);
    float rs = rsqrtf(var + 1e-5f);
    #pragma unroll
    for (int d = 0; d < 64; ++d) y[d] = (y[d] - mu) * rs * ps[d] + ps[64 + d];
    #pragma unroll
    for (int c = 0; c < 8; ++c) {
      FragU fu;
      #pragma unroll
      for (int u = 0; u < 4; ++u) fu.w[u] = pk2(y[c*8 + 2*u], y[c*8 + 2*u + 1]);
      *reinterpret_cast<short8*>(sm + 65536 + tid * 128 + ((c ^ (tid & 7)) << 4)) = fu.f;
    }
  }
  __syncthreads();

  // ---- phase 3: FFN per wave: h^T = relu(W1 y^T + bf1); z^T = W2 h^T ----
  {
    short8 yb[2][4];
    #pragma unroll
    for (int stl = 0; stl < 2; ++stl) {
      int row = wv * 64 + stl * 32 + l31;
      #pragma unroll
      for (int st = 0; st < 4; ++st)
        yb[stl][st] = *reinterpret_cast<const short8*>(
            sm + 65536 + row * 128 + ((((st << 1) | hi) ^ (row & 7)) << 4));
    }
    f32x16 zacc[2][2];
    #pragma unroll
    for (int i = 0; i < 16; ++i) {
      zacc[0][0][i] = 0.f; zacc[0][1][i] = 0.f; zacc[1][0][i] = 0.f; zacc[1][1][i] = 0.f;
    }
    #pragma clang loop unroll(disable)
    for (int jt = 0; jt < 8; ++jt) {
      short8 w1a[4];
      #pragma unroll
      for (int st = 0; st < 4; ++st)
        w1a[st] = ldg8(W1b + (size_t)(jt * 32 + l31) * 64 + st * 16 + hi * 8);
      short8 w2f[2][2];
      #pragma unroll
      for (int dt = 0; dt < 2; ++dt)
        #pragma unroll
        for (int ks = 0; ks < 2; ++ks)
          w2f[dt][ks] = ldg8(W2b + (size_t)(dt * 32 + l31) * 256 + jt * 32 + ks * 16 + hi * 8);
      float b1v[16];
      #pragma unroll
      for (int r = 0; r < 16; ++r)
        b1v[r] = ps[384 + jt * 32 + (r & 3) + 8 * (r >> 2) + 4 * hi];
      #pragma unroll
      for (int stl = 0; stl < 2; ++stl) {
        f32x16 ha = {};
        #pragma unroll
        for (int st = 0; st < 4; ++st)
          ha = __builtin_amdgcn_mfma_f32_32x32x16_bf16(w1a[st], yb[stl][st], ha, 0, 0, 0);
        float p[16];
        #pragma unroll
        for (int r = 0; r < 16; ++r) p[r] = fmaxf(ha[r] + b1v[r], 0.f);
        short8 b1, b2;
        repack(p, hi, b1, b2);
        zacc[0][stl] = __builtin_amdgcn_mfma_f32_32x32x16_bf16(w2f[0][0], b1, zacc[0][stl], 0, 0, 0);
        zacc[0][stl] = __builtin_amdgcn_mfma_f32_32x32x16_bf16(w2f[0][1], b2, zacc[0][stl], 0, 0, 0);
        zacc[1][stl] = __builtin_amdgcn_mfma_f32_32x32x16_bf16(w2f[1][0], b1, zacc[1][stl], 0, 0, 0);
        zacc[1][stl] = __builtin_amdgcn_mfma_f32_32x32x16_bf16(w2f[1][1], b2, zacc[1][stl], 0, 0, 0);
      }
    }
    // scatter z^T -> R1
    #pragma unroll
    for (int dt = 0; dt < 2; ++dt)
      #pragma unroll
      for (int stl = 0; stl < 2; ++stl) {
        int s_ = wv * 64 + stl * 32 + l31;
        #pragma unroll
        for (int rp = 0; rp < 8; ++rp) {
          int r = 2 * rp;
          int d = dt * 32 + (r & 3) + 8 * (r >> 2) + 4 * hi;
          *reinterpret_cast<unsigned*>(
              sm + s_ * 128 + (((d >> 3) ^ (s_ & 7)) << 4) + ((d & 7) << 1)) =
              pk2(zacc[dt][stl][r], zacc[dt][stl][r + 1]);
        }
      }
  }
  __syncthreads();

  // ---- phase 4: per-thread row: LN2(z + bf2 + y), transposed store ----
  {
    float z[64];
    #pragma unroll
    for (int c = 0; c < 8; ++c) {
      FragU zf, yf;
      zf.f = *reinterpret_cast<const short8*>(sm + tid * 128 + ((c ^ (tid & 7)) << 4));
      yf.f = *reinterpret_cast<const short8*>(sm + 65536 + tid * 128 + ((c ^ (tid & 7)) << 4));
      #pragma unroll
      for (int u = 0; u < 4; ++u) {
        int d = c * 8 + 2 * u;
        z[d]     = lo_f(zf.w[u]) + ps[192 + d]     + lo_f(yf.w[u]);
        z[d + 1] = hi_f(zf.w[u]) + ps[192 + d + 1] + hi_f(yf.w[u]);
      }
    }
    float m0 = 0.f, m1 = 0.f, m2 = 0.f, m3 = 0.f;
    #pragma unroll
    for (int j = 0; j < 16; ++j) {
      m0 += z[4*j+0]; m1 += z[4*j+1]; m2 += z[4*j+2]; m3 += z[4*j+3];
    }
    float mu2 = ((m0 + m1) + (m2 + m3)) * (1.f / 64.f);
    float v0 = 0.f, v1 = 0.f, v2 = 0.f, v3 = 0.f;
    #pragma unroll
    for (int j = 0; j < 16; ++j) {
      float t0 = z[4*j+0] - mu2, t1 = z[4*j+1] - mu2;
      float t2 = z[4*j+2] - mu2, t3 = z[4*j+3] - mu2;
      v0 = fmaf(t0, t0, v0); v1 = fmaf(t1, t1, v1);
      v2 = fmaf(t2, t2, v2); v3 = fmaf(t3, t3, v3);
    }
    float var2 = ((v0 + v1) + (v2 + v3)) * (1.f / 64.f);
    float rs2 = rsqrtf(var2 + 1e-5f);
    float4* op = reinterpret_cast<float4*>(out + ((size_t)tid * NT + t) * DIM);
    #pragma unroll
    for (int i = 0; i < 16; ++i) {
      op[i] = make_float4(
          (z[4*i+0] - mu2) * rs2 * ps[256 + 4*i+0] + ps[320 + 4*i+0],
          (z[4*i+1] - mu2) * rs2 * ps[256 + 4*i+1] + ps[320 + 4*i+1],
          (z[4*i+2] - mu2) * rs2 * ps[256 + 4*i+2] + ps[320 + 4*i+2],
          (z[4*i+3] - mu2) * rs2 * ps[256 + 4*i+3] + ps[320 + 4*i+3]);
    }
  }
}

extern "C" void kernel_launch(void* const* d_in, const int* in_sizes, int n_in,
                              void* d_out, int out_size, void* d_ws, size_t ws_size,
                              hipStream_t stream) {
  const float* x    = (const float*)d_in[0];
  const float* Wqkv = (const float*)d_in[1];
  const float* bqkv = (const float*)d_in[2];
  const float* Wo   = (const float*)d_in[3];
  const float* bo   = (const float*)d_in[4];
  const float* g1   = (const float*)d_in[5];
  const float* be1  = (const float*)d_in[6];
  const float* W1   = (const float*)d_in[7];
  const float* bf1  = (const float*)d_in[8];
  const float* W2   = (const float*)d_in[9];
  const float* bf2  = (const float*)d_in[10];
  const float* g2   = (const float*)d_in[11];
  const float* be2  = (const float*)d_in[12];
  float* out = (float*)d_out;

  // ws: bf16 weights [0,96KB) | ctx bf16 @128KB (32MB)
  __hip_bfloat16* wb   = (__hip_bfloat16*)d_ws;
  __hip_bfloat16* ctxb = (__hip_bfloat16*)((char*)d_ws + 131072);

  hipLaunchKernelGGL(k_cvt, dim3(192), dim3(256), 0, stream, Wqkv, Wo, W1, W2, wb);
  hipLaunchKernelGGL(k_attn, dim3(NT, 2), dim3(512), 0, stream, x, wb, bqkv, ctxb);
  hipLaunchKernelGGL(k_tail, dim3(NT), dim3(512), 0, stream,
                     ctxb, x, wb + 12288, bo, g1, be1, wb + 16384, bf1,
                     wb + 32768, bf2, g2, be2, out);
}